// Round 1
// baseline (572.138 us; speedup 1.0000x reference)
//
#include <hip/hip_runtime.h>
#include <hip/hip_bf16.h>

// Problem constants (from reference): x (B,C,NX,NY) fp32, coords (B,N,2) fp32
// out[b,c,n] = x[b,c, px*NY+py], px=trunc(clip(coords[b,n,1]*(NX-1),0,NX)),
//                                py=trunc(clip(coords[b,n,0]*(NY-1),0,NY))
#define B_  8
#define C_  128
#define NX_ 256
#define NY_ 256
#define N_  32768
#define PLANE_ (NX_ * NY_)   // 65536 floats per (b,c) plane

__global__ __launch_bounds__(256) void nu_grid_sampler_kernel(
    const float* __restrict__ x,
    const float* __restrict__ coords,
    float* __restrict__ out)
{
    const int n = blockIdx.x * blockDim.x + threadIdx.x;   // sample index within batch
    const int b = blockIdx.y;
    if (n >= N_) return;

    // coords[b, n, 0] = y-coord, coords[b, n, 1] = x-coord (per reference)
    const float2 cc = *reinterpret_cast<const float2*>(coords + ((size_t)b * N_ + n) * 2);
    const float cy = cc.x;
    const float cx = cc.y;

    // Match reference numerics: scale by (dim-1), clamp to [0, dim], trunc to int.
    const int px = (int)fminf(fmaxf(cx * (float)(NX_ - 1), 0.0f), (float)NX_);
    const int py = (int)fminf(fmaxf(cy * (float)(NY_ - 1), 0.0f), (float)NY_);
    // JAX take_along_axis clamps the flat index; mirror that for safety.
    const int idx = min(px * NY_ + py, PLANE_ - 1);

    const float* __restrict__ xb = x + (size_t)b * C_ * PLANE_ + idx;
    float* __restrict__ ob = out + (size_t)b * C_ * N_ + n;

    // Loop channels; 8 independent gathers in flight per iteration for latency
    // hiding. Stores are coalesced across threads (consecutive n); use
    // nontemporal stores so the streaming output doesn't evict gather lines
    // from L2.
    #pragma unroll
    for (int c0 = 0; c0 < C_; c0 += 8) {
        float v0 = xb[(size_t)(c0 + 0) * PLANE_];
        float v1 = xb[(size_t)(c0 + 1) * PLANE_];
        float v2 = xb[(size_t)(c0 + 2) * PLANE_];
        float v3 = xb[(size_t)(c0 + 3) * PLANE_];
        float v4 = xb[(size_t)(c0 + 4) * PLANE_];
        float v5 = xb[(size_t)(c0 + 5) * PLANE_];
        float v6 = xb[(size_t)(c0 + 6) * PLANE_];
        float v7 = xb[(size_t)(c0 + 7) * PLANE_];
        __builtin_nontemporal_store(v0, ob + (size_t)(c0 + 0) * N_);
        __builtin_nontemporal_store(v1, ob + (size_t)(c0 + 1) * N_);
        __builtin_nontemporal_store(v2, ob + (size_t)(c0 + 2) * N_);
        __builtin_nontemporal_store(v3, ob + (size_t)(c0 + 3) * N_);
        __builtin_nontemporal_store(v4, ob + (size_t)(c0 + 4) * N_);
        __builtin_nontemporal_store(v5, ob + (size_t)(c0 + 5) * N_);
        __builtin_nontemporal_store(v6, ob + (size_t)(c0 + 6) * N_);
        __builtin_nontemporal_store(v7, ob + (size_t)(c0 + 7) * N_);
    }
}

extern "C" void kernel_launch(void* const* d_in, const int* in_sizes, int n_in,
                              void* d_out, int out_size, void* d_ws, size_t ws_size,
                              hipStream_t stream) {
    const float* x      = (const float*)d_in[0];
    const float* coords = (const float*)d_in[1];
    float* out          = (float*)d_out;

    dim3 block(256);
    dim3 grid(N_ / 256, B_);   // 128 x 8 = 1024 blocks
    nu_grid_sampler_kernel<<<grid, block, 0, stream>>>(x, coords, out);
}

// Round 2
// 489.918 us; speedup vs baseline: 1.1678x; 1.1678x over previous
//
#include <hip/hip_runtime.h>
#include <hip/hip_bf16.h>

// out[b,c,n] = x[b,c, px*NY+py], px=trunc(clip(coords[b,n,1]*(NX-1),0,NX)),
//                                py=trunc(clip(coords[b,n,0]*(NY-1),0,NY))
//
// R2 strategy: L2-locality scheduling. 1-D grid decoded as:
//   b      = bid % 8      -> round-robin block->XCD => per-XCD batch affinity
//   n-chunk= fastest      -> XCD sweeps all N samples for a channel group
//   c-group= slowest      -> 8 planes live at a time = 2 MiB <= 4 MiB XCD L2
// All ~16 reuses of each 128B x-line happen within one window => each line
// fetched from HBM once. Ideal traffic: 256MiB read + 128MiB write.
#define B_  8
#define C_  128
#define NX_ 256
#define NY_ 256
#define N_  32768
#define PLANE_ (NX_ * NY_)      // 65536 floats per (b,c) plane
#define CG_  8                  // channels per group
#define NCG_ (C_ / CG_)         // 16 channel groups
#define NBLK_ (N_ / 256)        // 128 n-chunks of 256 samples

__global__ __launch_bounds__(256) void nu_grid_sampler_kernel(
    const float* __restrict__ x,
    const float* __restrict__ coords,
    float* __restrict__ out)
{
    const int bid  = blockIdx.x;          // 0 .. 8*16*128-1
    const int b    = bid & 7;             // XCD-affine batch
    const int rem  = bid >> 3;
    const int cg   = rem >> 7;            // channel group, slowest within XCD
    const int nblk = rem & (NBLK_ - 1);   // n-chunk, fastest within XCD

    const int n  = nblk * 256 + threadIdx.x;
    const int c0 = cg * CG_;

    // coords[b, n, 0] = y-coord, coords[b, n, 1] = x-coord (per reference)
    const float2 cc = *reinterpret_cast<const float2*>(coords + ((size_t)b * N_ + n) * 2);
    const float cy = cc.x;
    const float cx = cc.y;

    // Match reference numerics: scale by (dim-1), clamp to [0, dim], trunc.
    const int px = (int)fminf(fmaxf(cx * (float)(NX_ - 1), 0.0f), (float)NX_);
    const int py = (int)fminf(fmaxf(cy * (float)(NY_ - 1), 0.0f), (float)NY_);
    const int idx = min(px * NY_ + py, PLANE_ - 1);

    const float* __restrict__ xb = x + ((size_t)b * C_ + c0) * PLANE_ + idx;
    float* __restrict__ ob = out + ((size_t)b * C_ + c0) * N_ + n;

    // 8 independent gathers in flight (latency hiding); stores coalesced
    // across threads (consecutive n), nontemporal so the streaming output
    // doesn't evict gather lines from L2.
    float v0 = xb[(size_t)0 * PLANE_];
    float v1 = xb[(size_t)1 * PLANE_];
    float v2 = xb[(size_t)2 * PLANE_];
    float v3 = xb[(size_t)3 * PLANE_];
    float v4 = xb[(size_t)4 * PLANE_];
    float v5 = xb[(size_t)5 * PLANE_];
    float v6 = xb[(size_t)6 * PLANE_];
    float v7 = xb[(size_t)7 * PLANE_];
    __builtin_nontemporal_store(v0, ob + (size_t)0 * N_);
    __builtin_nontemporal_store(v1, ob + (size_t)1 * N_);
    __builtin_nontemporal_store(v2, ob + (size_t)2 * N_);
    __builtin_nontemporal_store(v3, ob + (size_t)3 * N_);
    __builtin_nontemporal_store(v4, ob + (size_t)4 * N_);
    __builtin_nontemporal_store(v5, ob + (size_t)5 * N_);
    __builtin_nontemporal_store(v6, ob + (size_t)6 * N_);
    __builtin_nontemporal_store(v7, ob + (size_t)7 * N_);
}

extern "C" void kernel_launch(void* const* d_in, const int* in_sizes, int n_in,
                              void* d_out, int out_size, void* d_ws, size_t ws_size,
                              hipStream_t stream) {
    const float* x      = (const float*)d_in[0];
    const float* coords = (const float*)d_in[1];
    float* out          = (float*)d_out;

    dim3 block(256);
    dim3 grid(B_ * NCG_ * NBLK_);   // 8 * 16 * 128 = 16384 blocks, 1-D for XCD swizzle
    nu_grid_sampler_kernel<<<grid, block, 0, stream>>>(x, coords, out);
}

// Round 3
// 460.629 us; speedup vs baseline: 1.2421x; 1.0636x over previous
//
#include <hip/hip_runtime.h>
#include <hip/hip_bf16.h>

// out[b,c,n] = x[b,c, px*NY+py], px=trunc(clip(coords[b,n,1]*(NX-1),0,NX)),
//                                py=trunc(clip(coords[b,n,0]*(NY-1),0,NY))
//
// R3: the R2 kernel is transaction-limited (33.5M per-lane random 4B gathers,
// ~4 cyc/line-transaction). Fix = channels-last staging in d_ws:
//   mark:      bitmap of touched positions (skip ~61% of transpose writes)
//   transpose: x (b,c,p) -> xT (b,p,c); LDS tile, coalesced both sides
//   gather:    per 64-sample block, read 512B-contiguous channel vectors
//              (4 line-transactions/wave vs 64), LDS transpose, coalesced
//              stores along n.
#define B_  8
#define C_  128
#define NX_ 256
#define NY_ 256
#define N_  32768
#define PLANE_ (NX_ * NY_)                       // 65536
#define XT_BYTES ((size_t)B_ * PLANE_ * C_ * 4)  // 268435456
#define BM_WORDS_PER_B (PLANE_ / 32)             // 2048
#define BM_BYTES ((size_t)B_ * BM_WORDS_PER_B * 4) // 65536

__device__ __forceinline__ int sample_idx(const float* __restrict__ coords, int b, int n) {
    const float2 cc = *reinterpret_cast<const float2*>(coords + ((size_t)b * N_ + n) * 2);
    const int px = (int)fminf(fmaxf(cc.y * (float)(NX_ - 1), 0.0f), (float)NX_);
    const int py = (int)fminf(fmaxf(cc.x * (float)(NY_ - 1), 0.0f), (float)NY_);
    return min(px * NY_ + py, PLANE_ - 1);
}

// ---- pass 0: mark touched positions ---------------------------------------
__global__ __launch_bounds__(256) void mark_kernel(const float* __restrict__ coords,
                                                   unsigned* __restrict__ bm) {
    const int n = blockIdx.x * 256 + threadIdx.x;
    const int b = blockIdx.y;
    const int idx = sample_idx(coords, b, n);
    atomicOr(&bm[b * BM_WORDS_PER_B + (idx >> 5)], 1u << (idx & 31));
}

// ---- pass 1: transpose (b,c,p) -> (b,p,c), touched positions only ---------
__global__ __launch_bounds__(256) void transpose_kernel(const float* __restrict__ x,
                                                        const unsigned* __restrict__ bm,
                                                        float* __restrict__ xT) {
    __shared__ float tile[32][129];              // stride 129: conflict-free both phases
    const int bid = blockIdx.x;
    const int b   = bid & 7;                     // XCD spread
    const int p0  = (bid >> 3) << 5;             // 32 positions per block
    const int t   = threadIdx.x;

    const float* __restrict__ xb = x + (size_t)b * C_ * PLANE_;
    const int pl = t & 31, cr = t >> 5;
    #pragma unroll
    for (int r = 0; r < 16; ++r) {               // read: lanes along p, coalesced
        const int c = r * 8 + cr;
        tile[pl][c] = xb[(size_t)c * PLANE_ + p0 + pl];
    }
    __syncthreads();

    float* __restrict__ xTb = xT + (size_t)b * PLANE_ * C_;
    const int c = t & 127, ph = t >> 7;
    #pragma unroll
    for (int r = 0; r < 16; ++r) {               // write: lanes along c, coalesced
        const int p = r * 2 + ph;                // wave-uniform p -> uniform branch
        const unsigned w = bm[b * BM_WORDS_PER_B + ((p0 + p) >> 5)];
        if (w & (1u << ((p0 + p) & 31)))
            xTb[(size_t)(p0 + p) * C_ + c] = tile[p][c];
    }
}

// ---- pass 2: gather 64 samples x 128 channels per block -------------------
__global__ __launch_bounds__(256) void gather_kernel(const float* __restrict__ xT,
                                                     const float* __restrict__ coords,
                                                     float* __restrict__ out) {
    __shared__ float smp[64][130];               // stride 130: 2-way (free) both phases
    __shared__ int   sidx[64];
    const int bid = blockIdx.x;
    const int b   = bid & 7;                     // XCD-affine batch
    const int n0  = (bid >> 3) << 6;             // 64 samples per block
    const int t   = threadIdx.x;

    if (t < 64) sidx[t] = sample_idx(coords, b, n0 + t);
    __syncthreads();

    // phase 1: each wave reads one sample's 512B channel vector (float2/lane)
    const float* __restrict__ xTb = xT + (size_t)b * PLANE_ * C_;
    const int g = t & 63, sr = t >> 6;
    #pragma unroll
    for (int r = 0; r < 16; ++r) {
        const int s = r * 4 + sr;
        const float2 v = *reinterpret_cast<const float2*>(&xTb[(size_t)sidx[s] * C_ + 2 * g]);
        *reinterpret_cast<float2*>(&smp[s][2 * g]) = v;
    }
    __syncthreads();

    // phase 2: lanes along samples -> coalesced stores per channel row
    float* __restrict__ ob = out + (size_t)b * C_ * N_ + n0;
    const int s = t & 63, ch = t >> 6;
    #pragma unroll
    for (int r = 0; r < 32; ++r) {
        const int c = r * 4 + ch;
        __builtin_nontemporal_store(smp[s][c], ob + (size_t)c * N_ + s);
    }
}

// ---- fallback (R2): direct gather, used only if ws too small --------------
__global__ __launch_bounds__(256) void fallback_kernel(const float* __restrict__ x,
                                                       const float* __restrict__ coords,
                                                       float* __restrict__ out) {
    const int bid  = blockIdx.x;
    const int b    = bid & 7;
    const int rem  = bid >> 3;
    const int cg   = rem >> 7;
    const int nblk = rem & 127;
    const int n  = nblk * 256 + threadIdx.x;
    const int c0 = cg * 8;
    const int idx = sample_idx(coords, b, n);
    const float* __restrict__ xb = x + ((size_t)b * C_ + c0) * PLANE_ + idx;
    float* __restrict__ ob = out + ((size_t)b * C_ + c0) * N_ + n;
    #pragma unroll
    for (int i = 0; i < 8; ++i)
        __builtin_nontemporal_store(xb[(size_t)i * PLANE_], ob + (size_t)i * N_);
}

extern "C" void kernel_launch(void* const* d_in, const int* in_sizes, int n_in,
                              void* d_out, int out_size, void* d_ws, size_t ws_size,
                              hipStream_t stream) {
    const float* x      = (const float*)d_in[0];
    const float* coords = (const float*)d_in[1];
    float* out          = (float*)d_out;

    if (ws_size >= XT_BYTES + BM_BYTES) {
        float*    xT = (float*)d_ws;
        unsigned* bm = (unsigned*)((char*)d_ws + XT_BYTES);
        hipMemsetAsync(bm, 0, BM_BYTES, stream);
        mark_kernel<<<dim3(N_ / 256, B_), 256, 0, stream>>>(coords, bm);
        transpose_kernel<<<B_ * (PLANE_ / 32), 256, 0, stream>>>(x, bm, xT);
        gather_kernel<<<B_ * (N_ / 64), 256, 0, stream>>>(xT, coords, out);
    } else {
        fallback_kernel<<<B_ * 16 * 128, 256, 0, stream>>>(x, coords, out);
    }
}